// Round 1
// 161.753 us; speedup vs baseline: 1.0072x; 1.0072x over previous
//
#include <hip/hip_runtime.h>

// RoIAlign forward, Detectron-style, sampling_ratio = 2.
// features: [N=2, C=256, H=200, W=200] fp32 ; rois: [1000,5] ; out: [1000,256,7,7]
//
// R9: (a) main kernel retiled to 8-channel uint4 tap loads (halves VMEM
// instruction count; 1 KB per wave-load) with 32-bit saddr offsets
// (row/col offsets premultiplied by FEAT_C in LDS -> 2 u32 adds per tap,
// no 64-bit address arithmetic per load). (b) transpose readout switched
// from 8x ds_read_u16 (8-way bank conflict) to 8x ds_read_b32 covering TWO
// spatials per thread (half the LDS instructions, 4-way max conflict).
// Transpose fill phase and all numerics are R8-identical.

#define POOLED_H 7
#define POOLED_W 7
#define SPATIAL_SCALE 0.0625f
#define FEAT_N 2
#define FEAT_C 256
#define FEAT_H 200
#define FEAT_W 200
#define FEAT_S (FEAT_H * FEAT_W)               // 40000
#define IMG_USH ((size_t)FEAT_S * FEAT_C)      // ushorts per image in NHWC

// transpose tile: 128 channels x 64 spatial
#define ST 64             // spatial floats per tile (40000/64 = 625 exact)
#define ST4 (ST / 4)      // 16 float4 per channel row
#define CT 128            // channels per tile: 128 bf16 = one full 256 B sector
#define SROW 66           // LDS row stride (ushorts) = 33 dwords

__device__ __forceinline__ unsigned short f2bf(float f) {
    unsigned int u = __float_as_uint(f);
    u += 0x7fffu + ((u >> 16) & 1u);   // round-to-nearest-even
    return (unsigned short)(u >> 16);
}

__device__ __forceinline__ float bflo(unsigned int u) { return __uint_as_float(u << 16); }
__device__ __forceinline__ float bfhi(unsigned int u) { return __uint_as_float(u & 0xffff0000u); }

// ---------- NCHW fp32 -> NHWC bf16 ----------
__global__ __launch_bounds__(256) void nchw_to_nhwc_bf16(
        const float* __restrict__ in, unsigned short* __restrict__ outp) {
    __shared__ unsigned short lds[CT * SROW];   // 16896 B
    const int s0 = blockIdx.x * ST;             // byte offset 256*bx -> 256 B aligned
    const int c0 = blockIdx.y * CT;
    const int b = blockIdx.z;
    const int tid = threadIdx.x;

    // ---- fill: 8 independent float4 loads into registers, then LDS ----
    const float* ibase = in + ((size_t)(b * FEAT_C + c0)) * FEAT_S + s0;
    float4 v[8];
#pragma unroll
    for (int k = 0; k < 8; ++k) {
        int f = tid + 256 * k;          // f < 2048 always
        int c = f >> 4;                 // /16 (power of 2, no div)
        int j = f & 15;
        v[k] = *(const float4*)(ibase + (size_t)c * FEAT_S + 4 * j);
    }
#pragma unroll
    for (int k = 0; k < 8; ++k) {
        int f = tid + 256 * k;
        int c = f >> 4;
        int j = f & 15;
        unsigned int p0 = (unsigned)f2bf(v[k].x) | ((unsigned)f2bf(v[k].y) << 16);
        unsigned int p1 = (unsigned)f2bf(v[k].z) | ((unsigned)f2bf(v[k].w) << 16);
        unsigned short* lp = &lds[c * SROW + 4 * j];
        *(unsigned int*)(lp) = p0;      // two b32 writes (row stride 132 B: uint2
        *(unsigned int*)(lp + 2) = p1;  //  would be 8B-misaligned for odd c)
    }
    __syncthreads();

    // ---- readout: two spatials per thread from 8 dword LDS reads ----
    // each d holds {spatial 2sp, 2sp+1} of one channel; repack to two
    // 256 B-sector uint4 stores (16 lanes x 16 B contiguous per spatial).
    unsigned short* obase = outp + ((size_t)b * FEAT_S + s0) * FEAT_C + c0;
#pragma unroll
    for (int k = 0; k < 2; ++k) {
        int f = tid + 256 * k;          // f < 512
        int sp = f >> 4;                // spatial pair 0..31
        int m = f & 15;                 // channels 8m..8m+7
        const unsigned short* lp = &lds[(8 * m) * SROW + 2 * sp];
        unsigned int d0 = *(const unsigned int*)(lp);
        unsigned int d1 = *(const unsigned int*)(lp + SROW);
        unsigned int d2 = *(const unsigned int*)(lp + 2 * SROW);
        unsigned int d3 = *(const unsigned int*)(lp + 3 * SROW);
        unsigned int d4 = *(const unsigned int*)(lp + 4 * SROW);
        unsigned int d5 = *(const unsigned int*)(lp + 5 * SROW);
        unsigned int d6 = *(const unsigned int*)(lp + 6 * SROW);
        unsigned int d7 = *(const unsigned int*)(lp + 7 * SROW);
        unsigned int w0 = (d0 & 0xffffu) | (d1 << 16);
        unsigned int w1 = (d2 & 0xffffu) | (d3 << 16);
        unsigned int w2 = (d4 & 0xffffu) | (d5 << 16);
        unsigned int w3 = (d6 & 0xffffu) | (d7 << 16);
        *(uint4*)(obase + (size_t)(2 * sp) * FEAT_C + 8 * m) = make_uint4(w0, w1, w2, w3);
        unsigned int u0 = (d0 >> 16) | (d1 & 0xffff0000u);
        unsigned int u1 = (d2 >> 16) | (d3 & 0xffff0000u);
        unsigned int u2 = (d4 >> 16) | (d5 & 0xffff0000u);
        unsigned int u3 = (d6 >> 16) | (d7 & 0xffff0000u);
        *(uint4*)(obase + (size_t)(2 * sp + 1) * FEAT_C + 8 * m) = make_uint4(u0, u1, u2, u3);
    }
}

// ---------- main: block = (roi, 64-channel quarter) ----------
__global__ __launch_bounds__(256) void roialign_main(
        const unsigned short* __restrict__ feat,   // [N,H,W,C] bf16
        const float* __restrict__ rois,
        float* __restrict__ out,
        int num_rois) {
    __shared__ float outbuf[64 * 49];              // 12544 B
    __shared__ unsigned int s_rowlo[14], s_rowhi[14];   // ylo/yhi * W * C
    __shared__ unsigned int s_collo[14], s_colhi[14];   // xlo/xhi * C
    __shared__ float s_ywl[14], s_ywh[14], s_xwl[14], s_xwh[14];

    const int bid = blockIdx.x;
    const int roi = bid >> 2;
    const int qc = (bid & 3) * 64;                 // channel quarter base

    const float* r = rois + roi * 5;
    const int b = (int)r[0];
    const float x1 = r[1] * SPATIAL_SCALE;
    const float y1 = r[2] * SPATIAL_SCALE;
    const float x2 = r[3] * SPATIAL_SCALE;
    const float y2 = r[4] * SPATIAL_SCALE;
    const float bin_w = fmaxf(x2 - x1, 1.0f) * (1.0f / POOLED_W);
    const float bin_h = fmaxf(y2 - y1, 1.0f) * (1.0f / POOLED_H);

    const int tid = threadIdx.x;
    if (tid < 14) {
        int p = tid >> 1, i = tid & 1;
        float yy = y1 + (float)p * bin_h + ((float)i + 0.5f) * bin_h * 0.5f;
        bool v = (yy > -1.0f) && (yy < (float)FEAT_H);
        float y = fmaxf(yy, 0.0f);
        int lo = min((int)floorf(y), FEAT_H - 1);
        int hi = min(lo + 1, FEAT_H - 1);
        if (lo >= FEAT_H - 1) y = (float)lo;       // edge snap (reference-exact)
        float l = y - (float)lo;
        s_rowlo[tid] = (unsigned)(lo * (FEAT_W * FEAT_C));
        s_rowhi[tid] = (unsigned)(hi * (FEAT_W * FEAT_C));
        s_ywl[tid] = v ? l : 0.0f;                 // validity folded into weights
        s_ywh[tid] = v ? (1.0f - l) : 0.0f;
    } else if (tid >= 64 && tid < 78) {
        int tt = tid - 64;
        int p = tt >> 1, i = tt & 1;
        float xx = x1 + (float)p * bin_w + ((float)i + 0.5f) * bin_w * 0.5f;
        bool v = (xx > -1.0f) && (xx < (float)FEAT_W);
        float x = fmaxf(xx, 0.0f);
        int lo = min((int)floorf(x), FEAT_W - 1);
        int hi = min(lo + 1, FEAT_W - 1);
        if (lo >= FEAT_W - 1) x = (float)lo;
        float l = x - (float)lo;
        s_collo[tt] = (unsigned)(lo * FEAT_C);
        s_colhi[tt] = (unsigned)(hi * FEAT_C);
        s_xwl[tt] = v ? l : 0.0f;
        s_xwh[tt] = v ? (1.0f - l) : 0.0f;
    }
    __syncthreads();

    const int g = tid & 7;           // channel octet: qc + 8g .. qc + 8g+7
    const int slot = tid >> 3;       // cell slot 0..31
    // 32-bit element offset of this thread's channel octet (fits: 20.5M ushorts)
    const unsigned int cbase = (unsigned)((size_t)b * IMG_USH) + (unsigned)(qc + 8 * g);

#pragma unroll
    for (int k = 0; k < 2; ++k) {
        const int s = slot + 32 * k;
        if (s < 49) {
            const int ph = (s * 37) >> 8;          // s/7 for s<49
            const int pw = s - ph * 7;
            float a0 = 0.f, a1 = 0.f, a2 = 0.f, a3 = 0.f;
            float a4 = 0.f, a5 = 0.f, a6 = 0.f, a7 = 0.f;
#pragma unroll
            for (int iy = 0; iy < 2; ++iy) {
                const int ky = ph * 2 + iy;
                const unsigned int rl = cbase + s_rowlo[ky];
                const unsigned int rh = cbase + s_rowhi[ky];
                const float wyl = s_ywl[ky];
                const float wyh = s_ywh[ky];
#pragma unroll
                for (int ix = 0; ix < 2; ++ix) {
                    const int kx = pw * 2 + ix;
                    const unsigned int cl = s_collo[kx];
                    const unsigned int ch = s_colhi[kx];
                    const float w00 = wyh * s_xwh[kx];
                    const float w01 = wyh * s_xwl[kx];
                    const float w10 = wyl * s_xwh[kx];
                    const float w11 = wyl * s_xwl[kx];
                    uint4 t00 = *(const uint4*)(feat + (size_t)(rl + cl));
                    uint4 t01 = *(const uint4*)(feat + (size_t)(rl + ch));
                    uint4 t10 = *(const uint4*)(feat + (size_t)(rh + cl));
                    uint4 t11 = *(const uint4*)(feat + (size_t)(rh + ch));
                    a0 += w00 * bflo(t00.x) + w01 * bflo(t01.x) + w10 * bflo(t10.x) + w11 * bflo(t11.x);
                    a1 += w00 * bfhi(t00.x) + w01 * bfhi(t01.x) + w10 * bfhi(t10.x) + w11 * bfhi(t11.x);
                    a2 += w00 * bflo(t00.y) + w01 * bflo(t01.y) + w10 * bflo(t10.y) + w11 * bflo(t11.y);
                    a3 += w00 * bfhi(t00.y) + w01 * bfhi(t01.y) + w10 * bfhi(t10.y) + w11 * bfhi(t11.y);
                    a4 += w00 * bflo(t00.z) + w01 * bflo(t01.z) + w10 * bflo(t10.z) + w11 * bflo(t11.z);
                    a5 += w00 * bfhi(t00.z) + w01 * bfhi(t01.z) + w10 * bfhi(t10.z) + w11 * bfhi(t11.z);
                    a6 += w00 * bflo(t00.w) + w01 * bflo(t01.w) + w10 * bflo(t10.w) + w11 * bflo(t11.w);
                    a7 += w00 * bfhi(t00.w) + w01 * bfhi(t01.w) + w10 * bfhi(t10.w) + w11 * bfhi(t11.w);
                }
            }
            const int cb = 8 * g;
            outbuf[(cb + 0) * 49 + s] = a0 * 0.25f;
            outbuf[(cb + 1) * 49 + s] = a1 * 0.25f;
            outbuf[(cb + 2) * 49 + s] = a2 * 0.25f;
            outbuf[(cb + 3) * 49 + s] = a3 * 0.25f;
            outbuf[(cb + 4) * 49 + s] = a4 * 0.25f;
            outbuf[(cb + 5) * 49 + s] = a5 * 0.25f;
            outbuf[(cb + 6) * 49 + s] = a6 * 0.25f;
            outbuf[(cb + 7) * 49 + s] = a7 * 0.25f;
        }
    }
    __syncthreads();

    // flat copy: 3136 floats = 784 float4, fully contiguous per block
    const float4* src = (const float4*)outbuf;
    float4* dst = (float4*)(out + (size_t)(roi * FEAT_C + qc) * 49);
    for (int i = tid; i < 784; i += 256) dst[i] = src[i];
}

// ---------- fallback (direct gather, no workspace) ----------
__device__ __forceinline__ float bilinear_tap(const float* __restrict__ plane,
                                              float y, float x) {
    const int H = FEAT_H, W = FEAT_W;
    if (!(y > -1.0f && y < (float)H && x > -1.0f && x < (float)W)) return 0.0f;
    y = fmaxf(y, 0.0f);
    x = fmaxf(x, 0.0f);
    int y0 = min((int)floorf(y), H - 1);
    int x0 = min((int)floorf(x), W - 1);
    int y1 = min(y0 + 1, H - 1);
    int x1 = min(x0 + 1, W - 1);
    if (y0 >= H - 1) y = (float)y0;
    if (x0 >= W - 1) x = (float)x0;
    float ly = y - (float)y0, lx = x - (float)x0;
    float hy = 1.0f - ly, hx = 1.0f - lx;
    return hy * (hx * plane[y0 * W + x0] + lx * plane[y0 * W + x1]) +
           ly * (hx * plane[y1 * W + x0] + lx * plane[y1 * W + x1]);
}

__global__ __launch_bounds__(256) void roialign_direct(
    const float* __restrict__ features, const float* __restrict__ rois,
    float* __restrict__ out, int num_rois) {
    int i = blockIdx.x * blockDim.x + threadIdx.x;
    int total = num_rois * FEAT_C * 49;
    if (i >= total) return;
    int s = i % 49;
    int t = i / 49;
    int c = t % FEAT_C;
    int roi = t / FEAT_C;
    int ph = s / POOLED_W, pw = s % POOLED_W;
    const float* r = rois + roi * 5;
    int b = (int)r[0];
    float x1 = r[1] * SPATIAL_SCALE, y1 = r[2] * SPATIAL_SCALE;
    float x2 = r[3] * SPATIAL_SCALE, y2 = r[4] * SPATIAL_SCALE;
    float bin_w = fmaxf(x2 - x1, 1.0f) * (1.0f / POOLED_W);
    float bin_h = fmaxf(y2 - y1, 1.0f) * (1.0f / POOLED_H);
    const float* plane = features + ((size_t)(b * FEAT_C + c)) * FEAT_S;
    float acc = 0.0f;
#pragma unroll
    for (int iy = 0; iy < 2; ++iy) {
        float yy = y1 + (float)ph * bin_h + ((float)iy + 0.5f) * bin_h * 0.5f;
#pragma unroll
        for (int ix = 0; ix < 2; ++ix) {
            float xx = x1 + (float)pw * bin_w + ((float)ix + 0.5f) * bin_w * 0.5f;
            acc += bilinear_tap(plane, yy, xx);
        }
    }
    out[i] = acc * 0.25f;
}

extern "C" void kernel_launch(void* const* d_in, const int* in_sizes, int n_in,
                              void* d_out, int out_size, void* d_ws, size_t ws_size,
                              hipStream_t stream) {
    const float* features = (const float*)d_in[0];
    const float* rois = (const float*)d_in[1];
    float* out = (float*)d_out;
    int num_rois = in_sizes[1] / 5;
    size_t need = (size_t)FEAT_N * IMG_USH * sizeof(unsigned short);  // ~41 MB
    if (ws_size >= need) {
        unsigned short* nhwc = (unsigned short*)d_ws;
        nchw_to_nhwc_bf16<<<dim3(FEAT_S / ST, FEAT_C / CT, FEAT_N), 256, 0, stream>>>(
            features, nhwc);
        roialign_main<<<num_rois * 4, 256, 0, stream>>>(nhwc, rois, out, num_rois);
    } else {
        int total = num_rois * FEAT_C * 49;
        roialign_direct<<<(total + 255) / 256, 256, 0, stream>>>(features, rois, out,
                                                                 num_rois);
    }
}

// Round 2
// 160.174 us; speedup vs baseline: 1.0171x; 1.0099x over previous
//
#include <hip/hip_runtime.h>

// RoIAlign forward, Detectron-style, sampling_ratio = 2.
// features: [N=2, C=256, H=200, W=200] fp32 ; rois: [1000,5] ; out: [1000,256,7,7]
//
// R10: roi spatial-locality sort + XCD-chunked dispatch.
//  - tiny counting-sort kernel (1 block) bins rois by (batch, 8x8 cell of roi
//    center) -> permutation in ws. Spatially overlapping rois become adjacent.
//  - main kernel walks rois through the permutation, with the bijective
//    chunked blockIdx transform (bid%8 -> chunk) so each XCD's L2 sees a
//    contiguous band of sorted rois -> overlapping tap regions hit L2 instead
//    of streaming from L3.  Main inner loop is R9-identical (verified).
//  - transpose kernel unchanged (R8/R9-verified, BW-floor).

#define POOLED_H 7
#define POOLED_W 7
#define SPATIAL_SCALE 0.0625f
#define FEAT_N 2
#define FEAT_C 256
#define FEAT_H 200
#define FEAT_W 200
#define FEAT_S (FEAT_H * FEAT_W)               // 40000
#define IMG_USH ((size_t)FEAT_S * FEAT_C)      // ushorts per image in NHWC

// transpose tile: 128 channels x 64 spatial
#define ST 64             // spatial floats per tile (40000/64 = 625 exact)
#define ST4 (ST / 4)      // 16 float4 per channel row
#define CT 128            // channels per tile: 128 bf16 = one full 256 B sector
#define SROW 66           // LDS row stride (ushorts) = 33 dwords

#define NBINS 128         // 2 batches x 8y x 8x locality bins

__device__ __forceinline__ unsigned short f2bf(float f) {
    unsigned int u = __float_as_uint(f);
    u += 0x7fffu + ((u >> 16) & 1u);   // round-to-nearest-even
    return (unsigned short)(u >> 16);
}

__device__ __forceinline__ float bflo(unsigned int u) { return __uint_as_float(u << 16); }
__device__ __forceinline__ float bfhi(unsigned int u) { return __uint_as_float(u & 0xffff0000u); }

// ---------- roi locality sort: counting sort by (batch, ycell, xcell) ----------
__device__ __forceinline__ int roi_bin(const float* __restrict__ r) {
    int b = (int)r[0];
    b = min(max(b, 0), FEAT_N - 1);
    float cy = (r[2] + r[4]) * 0.5f * SPATIAL_SCALE;   // feature space
    float cx = (r[1] + r[3]) * 0.5f * SPATIAL_SCALE;
    int yc = min(max((int)(cy * (8.0f / (float)FEAT_H)), 0), 7);
    int xc = min(max((int)(cx * (8.0f / (float)FEAT_W)), 0), 7);
    return (b << 6) | (yc << 3) | xc;
}

__global__ __launch_bounds__(1024) void roi_sort(
        const float* __restrict__ rois, int num_rois, int* __restrict__ perm) {
    __shared__ int hist[NBINS];
    const int tid = threadIdx.x;
    if (tid < NBINS) hist[tid] = 0;
    __syncthreads();
    for (int i = tid; i < num_rois; i += 1024)
        atomicAdd(&hist[roi_bin(rois + i * 5)], 1);
    __syncthreads();
    if (tid == 0) {                       // exclusive prefix over 128 bins
        int acc = 0;
        for (int i = 0; i < NBINS; ++i) { int c = hist[i]; hist[i] = acc; acc += c; }
    }
    __syncthreads();
    for (int i = tid; i < num_rois; i += 1024) {
        int pos = atomicAdd(&hist[roi_bin(rois + i * 5)], 1);
        perm[pos] = i;                    // any order within a bin is fine
    }
}

// ---------- NCHW fp32 -> NHWC bf16 ----------
__global__ __launch_bounds__(256) void nchw_to_nhwc_bf16(
        const float* __restrict__ in, unsigned short* __restrict__ outp) {
    __shared__ unsigned short lds[CT * SROW];   // 16896 B
    const int s0 = blockIdx.x * ST;             // byte offset 256*bx -> 256 B aligned
    const int c0 = blockIdx.y * CT;
    const int b = blockIdx.z;
    const int tid = threadIdx.x;

    // ---- fill: 8 independent float4 loads into registers, then LDS ----
    const float* ibase = in + ((size_t)(b * FEAT_C + c0)) * FEAT_S + s0;
    float4 v[8];
#pragma unroll
    for (int k = 0; k < 8; ++k) {
        int f = tid + 256 * k;          // f < 2048 always
        int c = f >> 4;                 // /16 (power of 2, no div)
        int j = f & 15;
        v[k] = *(const float4*)(ibase + (size_t)c * FEAT_S + 4 * j);
    }
#pragma unroll
    for (int k = 0; k < 8; ++k) {
        int f = tid + 256 * k;
        int c = f >> 4;
        int j = f & 15;
        unsigned int p0 = (unsigned)f2bf(v[k].x) | ((unsigned)f2bf(v[k].y) << 16);
        unsigned int p1 = (unsigned)f2bf(v[k].z) | ((unsigned)f2bf(v[k].w) << 16);
        unsigned short* lp = &lds[c * SROW + 4 * j];
        *(unsigned int*)(lp) = p0;      // two b32 writes (row stride 132 B: uint2
        *(unsigned int*)(lp + 2) = p1;  //  would be 8B-misaligned for odd c)
    }
    __syncthreads();

    // ---- readout: two spatials per thread from 8 dword LDS reads ----
    unsigned short* obase = outp + ((size_t)b * FEAT_S + s0) * FEAT_C + c0;
#pragma unroll
    for (int k = 0; k < 2; ++k) {
        int f = tid + 256 * k;          // f < 512
        int sp = f >> 4;                // spatial pair 0..31
        int m = f & 15;                 // channels 8m..8m+7
        const unsigned short* lp = &lds[(8 * m) * SROW + 2 * sp];
        unsigned int d0 = *(const unsigned int*)(lp);
        unsigned int d1 = *(const unsigned int*)(lp + SROW);
        unsigned int d2 = *(const unsigned int*)(lp + 2 * SROW);
        unsigned int d3 = *(const unsigned int*)(lp + 3 * SROW);
        unsigned int d4 = *(const unsigned int*)(lp + 4 * SROW);
        unsigned int d5 = *(const unsigned int*)(lp + 5 * SROW);
        unsigned int d6 = *(const unsigned int*)(lp + 6 * SROW);
        unsigned int d7 = *(const unsigned int*)(lp + 7 * SROW);
        unsigned int w0 = (d0 & 0xffffu) | (d1 << 16);
        unsigned int w1 = (d2 & 0xffffu) | (d3 << 16);
        unsigned int w2 = (d4 & 0xffffu) | (d5 << 16);
        unsigned int w3 = (d6 & 0xffffu) | (d7 << 16);
        *(uint4*)(obase + (size_t)(2 * sp) * FEAT_C + 8 * m) = make_uint4(w0, w1, w2, w3);
        unsigned int u0 = (d0 >> 16) | (d1 & 0xffff0000u);
        unsigned int u1 = (d2 >> 16) | (d3 & 0xffff0000u);
        unsigned int u2 = (d4 >> 16) | (d5 & 0xffff0000u);
        unsigned int u3 = (d6 >> 16) | (d7 & 0xffff0000u);
        *(uint4*)(obase + (size_t)(2 * sp + 1) * FEAT_C + 8 * m) = make_uint4(u0, u1, u2, u3);
    }
}

// ---------- main: block = (sorted roi, 64-channel quarter) ----------
__global__ __launch_bounds__(256) void roialign_main(
        const unsigned short* __restrict__ feat,   // [N,H,W,C] bf16
        const float* __restrict__ rois,
        const int* __restrict__ perm,              // sorted roi order
        float* __restrict__ out,
        int num_rois) {
    __shared__ float outbuf[64 * 49];              // 12544 B
    __shared__ unsigned int s_rowlo[14], s_rowhi[14];   // ylo/yhi * W * C
    __shared__ unsigned int s_collo[14], s_colhi[14];   // xlo/xhi * C
    __shared__ float s_ywl[14], s_ywh[14], s_xwl[14], s_xwh[14];

    // bijective chunked XCD transform: each XCD gets a contiguous band of
    // sorted rois (valid since gridDim.x % 8 == 0; identity fallback else).
    int bid = blockIdx.x;
    const int nwg = gridDim.x;
    if ((nwg & 7) == 0) {
        const int cpx = nwg >> 3;
        bid = (bid & 7) * cpx + (bid >> 3);
    }
    const int roi = perm[bid >> 2];                // true roi id
    const int qc = (bid & 3) * 64;                 // channel quarter base

    const float* r = rois + roi * 5;
    const int b = (int)r[0];
    const float x1 = r[1] * SPATIAL_SCALE;
    const float y1 = r[2] * SPATIAL_SCALE;
    const float x2 = r[3] * SPATIAL_SCALE;
    const float y2 = r[4] * SPATIAL_SCALE;
    const float bin_w = fmaxf(x2 - x1, 1.0f) * (1.0f / POOLED_W);
    const float bin_h = fmaxf(y2 - y1, 1.0f) * (1.0f / POOLED_H);

    const int tid = threadIdx.x;
    if (tid < 14) {
        int p = tid >> 1, i = tid & 1;
        float yy = y1 + (float)p * bin_h + ((float)i + 0.5f) * bin_h * 0.5f;
        bool v = (yy > -1.0f) && (yy < (float)FEAT_H);
        float y = fmaxf(yy, 0.0f);
        int lo = min((int)floorf(y), FEAT_H - 1);
        int hi = min(lo + 1, FEAT_H - 1);
        if (lo >= FEAT_H - 1) y = (float)lo;       // edge snap (reference-exact)
        float l = y - (float)lo;
        s_rowlo[tid] = (unsigned)(lo * (FEAT_W * FEAT_C));
        s_rowhi[tid] = (unsigned)(hi * (FEAT_W * FEAT_C));
        s_ywl[tid] = v ? l : 0.0f;                 // validity folded into weights
        s_ywh[tid] = v ? (1.0f - l) : 0.0f;
    } else if (tid >= 64 && tid < 78) {
        int tt = tid - 64;
        int p = tt >> 1, i = tt & 1;
        float xx = x1 + (float)p * bin_w + ((float)i + 0.5f) * bin_w * 0.5f;
        bool v = (xx > -1.0f) && (xx < (float)FEAT_W);
        float x = fmaxf(xx, 0.0f);
        int lo = min((int)floorf(x), FEAT_W - 1);
        int hi = min(lo + 1, FEAT_W - 1);
        if (lo >= FEAT_W - 1) x = (float)lo;
        float l = x - (float)lo;
        s_collo[tt] = (unsigned)(lo * FEAT_C);
        s_colhi[tt] = (unsigned)(hi * FEAT_C);
        s_xwl[tt] = v ? l : 0.0f;
        s_xwh[tt] = v ? (1.0f - l) : 0.0f;
    }
    __syncthreads();

    const int g = tid & 7;           // channel octet: qc + 8g .. qc + 8g+7
    const int slot = tid >> 3;       // cell slot 0..31
    // 32-bit element offset of this thread's channel octet (fits: 20.5M ushorts)
    const unsigned int cbase = (unsigned)((size_t)b * IMG_USH) + (unsigned)(qc + 8 * g);

#pragma unroll
    for (int k = 0; k < 2; ++k) {
        const int s = slot + 32 * k;
        if (s < 49) {
            const int ph = (s * 37) >> 8;          // s/7 for s<49
            const int pw = s - ph * 7;
            float a0 = 0.f, a1 = 0.f, a2 = 0.f, a3 = 0.f;
            float a4 = 0.f, a5 = 0.f, a6 = 0.f, a7 = 0.f;
#pragma unroll
            for (int iy = 0; iy < 2; ++iy) {
                const int ky = ph * 2 + iy;
                const unsigned int rl = cbase + s_rowlo[ky];
                const unsigned int rh = cbase + s_rowhi[ky];
                const float wyl = s_ywl[ky];
                const float wyh = s_ywh[ky];
#pragma unroll
                for (int ix = 0; ix < 2; ++ix) {
                    const int kx = pw * 2 + ix;
                    const unsigned int cl = s_collo[kx];
                    const unsigned int ch = s_colhi[kx];
                    const float w00 = wyh * s_xwh[kx];
                    const float w01 = wyh * s_xwl[kx];
                    const float w10 = wyl * s_xwh[kx];
                    const float w11 = wyl * s_xwl[kx];
                    uint4 t00 = *(const uint4*)(feat + (size_t)(rl + cl));
                    uint4 t01 = *(const uint4*)(feat + (size_t)(rl + ch));
                    uint4 t10 = *(const uint4*)(feat + (size_t)(rh + cl));
                    uint4 t11 = *(const uint4*)(feat + (size_t)(rh + ch));
                    a0 += w00 * bflo(t00.x) + w01 * bflo(t01.x) + w10 * bflo(t10.x) + w11 * bflo(t11.x);
                    a1 += w00 * bfhi(t00.x) + w01 * bfhi(t01.x) + w10 * bfhi(t10.x) + w11 * bfhi(t11.x);
                    a2 += w00 * bflo(t00.y) + w01 * bflo(t01.y) + w10 * bflo(t10.y) + w11 * bflo(t11.y);
                    a3 += w00 * bfhi(t00.y) + w01 * bfhi(t01.y) + w10 * bfhi(t10.y) + w11 * bfhi(t11.y);
                    a4 += w00 * bflo(t00.z) + w01 * bflo(t01.z) + w10 * bflo(t10.z) + w11 * bflo(t11.z);
                    a5 += w00 * bfhi(t00.z) + w01 * bfhi(t01.z) + w10 * bfhi(t10.z) + w11 * bfhi(t11.z);
                    a6 += w00 * bflo(t00.w) + w01 * bflo(t01.w) + w10 * bflo(t10.w) + w11 * bflo(t11.w);
                    a7 += w00 * bfhi(t00.w) + w01 * bfhi(t01.w) + w10 * bfhi(t10.w) + w11 * bfhi(t11.w);
                }
            }
            const int cb = 8 * g;
            outbuf[(cb + 0) * 49 + s] = a0 * 0.25f;
            outbuf[(cb + 1) * 49 + s] = a1 * 0.25f;
            outbuf[(cb + 2) * 49 + s] = a2 * 0.25f;
            outbuf[(cb + 3) * 49 + s] = a3 * 0.25f;
            outbuf[(cb + 4) * 49 + s] = a4 * 0.25f;
            outbuf[(cb + 5) * 49 + s] = a5 * 0.25f;
            outbuf[(cb + 6) * 49 + s] = a6 * 0.25f;
            outbuf[(cb + 7) * 49 + s] = a7 * 0.25f;
        }
    }
    __syncthreads();

    // flat copy: 3136 floats = 784 float4, fully contiguous per block
    const float4* src = (const float4*)outbuf;
    float4* dst = (float4*)(out + (size_t)(roi * FEAT_C + qc) * 49);
    for (int i = tid; i < 784; i += 256) dst[i] = src[i];
}

// ---------- fallback (direct gather, no workspace) ----------
__device__ __forceinline__ float bilinear_tap(const float* __restrict__ plane,
                                              float y, float x) {
    const int H = FEAT_H, W = FEAT_W;
    if (!(y > -1.0f && y < (float)H && x > -1.0f && x < (float)W)) return 0.0f;
    y = fmaxf(y, 0.0f);
    x = fmaxf(x, 0.0f);
    int y0 = min((int)floorf(y), H - 1);
    int x0 = min((int)floorf(x), W - 1);
    int y1 = min(y0 + 1, H - 1);
    int x1 = min(x0 + 1, W - 1);
    if (y0 >= H - 1) y = (float)y0;
    if (x0 >= W - 1) x = (float)x0;
    float ly = y - (float)y0, lx = x - (float)x0;
    float hy = 1.0f - ly, hx = 1.0f - lx;
    return hy * (hx * plane[y0 * W + x0] + lx * plane[y0 * W + x1]) +
           ly * (hx * plane[y1 * W + x0] + lx * plane[y1 * W + x1]);
}

__global__ __launch_bounds__(256) void roialign_direct(
    const float* __restrict__ features, const float* __restrict__ rois,
    float* __restrict__ out, int num_rois) {
    int i = blockIdx.x * blockDim.x + threadIdx.x;
    int total = num_rois * FEAT_C * 49;
    if (i >= total) return;
    int s = i % 49;
    int t = i / 49;
    int c = t % FEAT_C;
    int roi = t / FEAT_C;
    int ph = s / POOLED_W, pw = s % POOLED_W;
    const float* r = rois + roi * 5;
    int b = (int)r[0];
    float x1 = r[1] * SPATIAL_SCALE, y1 = r[2] * SPATIAL_SCALE;
    float x2 = r[3] * SPATIAL_SCALE, y2 = r[4] * SPATIAL_SCALE;
    float bin_w = fmaxf(x2 - x1, 1.0f) * (1.0f / POOLED_W);
    float bin_h = fmaxf(y2 - y1, 1.0f) * (1.0f / POOLED_H);
    const float* plane = features + ((size_t)(b * FEAT_C + c)) * FEAT_S;
    float acc = 0.0f;
#pragma unroll
    for (int iy = 0; iy < 2; ++iy) {
        float yy = y1 + (float)ph * bin_h + ((float)iy + 0.5f) * bin_h * 0.5f;
#pragma unroll
        for (int ix = 0; ix < 2; ++ix) {
            float xx = x1 + (float)pw * bin_w + ((float)ix + 0.5f) * bin_w * 0.5f;
            acc += bilinear_tap(plane, yy, xx);
        }
    }
    out[i] = acc * 0.25f;
}

extern "C" void kernel_launch(void* const* d_in, const int* in_sizes, int n_in,
                              void* d_out, int out_size, void* d_ws, size_t ws_size,
                              hipStream_t stream) {
    const float* features = (const float*)d_in[0];
    const float* rois = (const float*)d_in[1];
    float* out = (float*)d_out;
    int num_rois = in_sizes[1] / 5;
    size_t nhwc_bytes = (size_t)FEAT_N * IMG_USH * sizeof(unsigned short);  // ~41 MB
    size_t need = nhwc_bytes + (size_t)num_rois * sizeof(int);
    if (ws_size >= need) {
        unsigned short* nhwc = (unsigned short*)d_ws;
        int* perm = (int*)((char*)d_ws + nhwc_bytes);
        roi_sort<<<1, 1024, 0, stream>>>(rois, num_rois, perm);
        nchw_to_nhwc_bf16<<<dim3(FEAT_S / ST, FEAT_C / CT, FEAT_N), 256, 0, stream>>>(
            features, nhwc);
        roialign_main<<<num_rois * 4, 256, 0, stream>>>(nhwc, rois, perm, out, num_rois);
    } else {
        int total = num_rois * FEAT_C * 49;
        roialign_direct<<<(total + 255) / 256, 256, 0, stream>>>(features, rois, out,
                                                                 num_rois);
    }
}

// Round 3
// 157.841 us; speedup vs baseline: 1.0322x; 1.0148x over previous
//
#include <hip/hip_runtime.h>

// RoIAlign forward, Detectron-style, sampling_ratio = 2.
// features: [N=2, C=256, H=200, W=200] fp32 ; rois: [1000,5] ; out: [1000,256,7,7]
//
// R11: (a) transpose grid flattened to 1D + bijective XCD-chunked so each XCD
// reads a CONTIGUOUS band of 256 B spatial chunks (sequential HBM runs per
// channel row instead of device-wide 256 B scatter); (b) roi locality sort
// folded into transpose block 0 (runs in the shadow of the other 2499 blocks,
// saves one launch). Main kernel is R10-identical (verified).

#define POOLED_H 7
#define POOLED_W 7
#define SPATIAL_SCALE 0.0625f
#define FEAT_N 2
#define FEAT_C 256
#define FEAT_H 200
#define FEAT_W 200
#define FEAT_S (FEAT_H * FEAT_W)               // 40000
#define IMG_USH ((size_t)FEAT_S * FEAT_C)      // ushorts per image in NHWC

// transpose tile: 128 channels x 64 spatial
#define ST 64             // spatial floats per tile (40000/64 = 625 exact)
#define ST4 (ST / 4)      // 16 float4 per channel row
#define CT 128            // channels per tile: 128 bf16 = one full 256 B sector
#define SROW 66           // LDS row stride (ushorts) = 33 dwords
#define NTILE_S (FEAT_S / ST)                  // 625 spatial tiles
#define NTILE (NTILE_S * (FEAT_C / CT) * FEAT_N)   // 2500 blocks

#define NBINS 128         // 2 batches x 8y x 8x locality bins

__device__ __forceinline__ unsigned short f2bf(float f) {
    unsigned int u = __float_as_uint(f);
    u += 0x7fffu + ((u >> 16) & 1u);   // round-to-nearest-even
    return (unsigned short)(u >> 16);
}

__device__ __forceinline__ float bflo(unsigned int u) { return __uint_as_float(u << 16); }
__device__ __forceinline__ float bfhi(unsigned int u) { return __uint_as_float(u & 0xffff0000u); }

__device__ __forceinline__ int roi_bin(const float* __restrict__ r) {
    int b = (int)r[0];
    b = min(max(b, 0), FEAT_N - 1);
    float cy = (r[2] + r[4]) * 0.5f * SPATIAL_SCALE;   // feature space
    float cx = (r[1] + r[3]) * 0.5f * SPATIAL_SCALE;
    int yc = min(max((int)(cy * (8.0f / (float)FEAT_H)), 0), 7);
    int xc = min(max((int)(cx * (8.0f / (float)FEAT_W)), 0), 7);
    return (b << 6) | (yc << 3) | xc;
}

// ---------- NCHW fp32 -> NHWC bf16 (+ roi sort in block 0) ----------
__global__ __launch_bounds__(256) void nchw_to_nhwc_bf16(
        const float* __restrict__ in, unsigned short* __restrict__ outp,
        const float* __restrict__ rois, int num_rois, int* __restrict__ perm) {
    __shared__ unsigned short lds[CT * SROW];   // 16896 B
    __shared__ int hist[NBINS];                 // 512 B (sort, block 0 only)

    // bijective XCD chunk transform for NTILE = 2500 = 8*312 + 4 (m204 form):
    // xcd = orig%8 owns a contiguous band of wgids -> sequential spatial runs.
    const int orig = blockIdx.x;
    const int q = NTILE >> 3, r = NTILE & 7;    // 312, 4
    const int xcd = orig & 7;
    const int base = (xcd < r) ? xcd * (q + 1) : r * (q + 1) + (xcd - r) * q;
    const int wgid = base + (orig >> 3);
    // decompose: contiguous wgid = contiguous spatial within one (ctile, batch)
    const int sx = wgid % NTILE_S;
    const int cb = wgid / NTILE_S;              // 0..3
    const int s0 = sx * ST;
    const int c0 = (cb & 1) * CT;
    const int b = cb >> 1;
    const int tid = threadIdx.x;

    // ---- fill: 8 independent float4 loads into registers, then LDS ----
    const float* ibase = in + ((size_t)(b * FEAT_C + c0)) * FEAT_S + s0;
    float4 v[8];
#pragma unroll
    for (int k = 0; k < 8; ++k) {
        int f = tid + 256 * k;          // f < 2048 always
        int c = f >> 4;                 // /16 (power of 2, no div)
        int j = f & 15;
        v[k] = *(const float4*)(ibase + (size_t)c * FEAT_S + 4 * j);
    }
#pragma unroll
    for (int k = 0; k < 8; ++k) {
        int f = tid + 256 * k;
        int c = f >> 4;
        int j = f & 15;
        unsigned int p0 = (unsigned)f2bf(v[k].x) | ((unsigned)f2bf(v[k].y) << 16);
        unsigned int p1 = (unsigned)f2bf(v[k].z) | ((unsigned)f2bf(v[k].w) << 16);
        unsigned short* lp = &lds[c * SROW + 4 * j];
        *(unsigned int*)(lp) = p0;      // two b32 writes (row stride 132 B: uint2
        *(unsigned int*)(lp + 2) = p1;  //  would be 8B-misaligned for odd c)
    }
    __syncthreads();

    // ---- readout: two spatials per thread from 8 dword LDS reads ----
    unsigned short* obase = outp + ((size_t)b * FEAT_S + s0) * FEAT_C + c0;
#pragma unroll
    for (int k = 0; k < 2; ++k) {
        int f = tid + 256 * k;          // f < 512
        int sp = f >> 4;                // spatial pair 0..31
        int m = f & 15;                 // channels 8m..8m+7
        const unsigned short* lp = &lds[(8 * m) * SROW + 2 * sp];
        unsigned int d0 = *(const unsigned int*)(lp);
        unsigned int d1 = *(const unsigned int*)(lp + SROW);
        unsigned int d2 = *(const unsigned int*)(lp + 2 * SROW);
        unsigned int d3 = *(const unsigned int*)(lp + 3 * SROW);
        unsigned int d4 = *(const unsigned int*)(lp + 4 * SROW);
        unsigned int d5 = *(const unsigned int*)(lp + 5 * SROW);
        unsigned int d6 = *(const unsigned int*)(lp + 6 * SROW);
        unsigned int d7 = *(const unsigned int*)(lp + 7 * SROW);
        unsigned int w0 = (d0 & 0xffffu) | (d1 << 16);
        unsigned int w1 = (d2 & 0xffffu) | (d3 << 16);
        unsigned int w2 = (d4 & 0xffffu) | (d5 << 16);
        unsigned int w3 = (d6 & 0xffffu) | (d7 << 16);
        *(uint4*)(obase + (size_t)(2 * sp) * FEAT_C + 8 * m) = make_uint4(w0, w1, w2, w3);
        unsigned int u0 = (d0 >> 16) | (d1 & 0xffff0000u);
        unsigned int u1 = (d2 >> 16) | (d3 & 0xffff0000u);
        unsigned int u2 = (d4 >> 16) | (d5 & 0xffff0000u);
        unsigned int u3 = (d6 >> 16) | (d7 & 0xffff0000u);
        *(uint4*)(obase + (size_t)(2 * sp + 1) * FEAT_C + 8 * m) = make_uint4(u0, u1, u2, u3);
    }

    // ---- roi locality sort, block 0 only (uniform branch; hides under grid) ----
    if (orig == 0) {
        if (tid < NBINS) hist[tid] = 0;
        __syncthreads();
        for (int i = tid; i < num_rois; i += 256)
            atomicAdd(&hist[roi_bin(rois + i * 5)], 1);
        __syncthreads();
        if (tid == 0) {                       // exclusive prefix over 128 bins
            int acc = 0;
            for (int i = 0; i < NBINS; ++i) { int c = hist[i]; hist[i] = acc; acc += c; }
        }
        __syncthreads();
        for (int i = tid; i < num_rois; i += 256) {
            int pos = atomicAdd(&hist[roi_bin(rois + i * 5)], 1);
            perm[pos] = i;                    // any order within a bin is fine
        }
    }
}

// ---------- main: block = (sorted roi, 64-channel quarter) ----------
__global__ __launch_bounds__(256) void roialign_main(
        const unsigned short* __restrict__ feat,   // [N,H,W,C] bf16
        const float* __restrict__ rois,
        const int* __restrict__ perm,              // sorted roi order
        float* __restrict__ out,
        int num_rois) {
    __shared__ float outbuf[64 * 49];              // 12544 B
    __shared__ unsigned int s_rowlo[14], s_rowhi[14];   // ylo/yhi * W * C
    __shared__ unsigned int s_collo[14], s_colhi[14];   // xlo/xhi * C
    __shared__ float s_ywl[14], s_ywh[14], s_xwl[14], s_xwh[14];

    // bijective chunked XCD transform (gridDim.x % 8 == 0 here; identity else)
    int bid = blockIdx.x;
    const int nwg = gridDim.x;
    if ((nwg & 7) == 0) {
        const int cpx = nwg >> 3;
        bid = (bid & 7) * cpx + (bid >> 3);
    }
    const int roi = perm[bid >> 2];                // true roi id
    const int qc = (bid & 3) * 64;                 // channel quarter base

    const float* r = rois + roi * 5;
    const int b = (int)r[0];
    const float x1 = r[1] * SPATIAL_SCALE;
    const float y1 = r[2] * SPATIAL_SCALE;
    const float x2 = r[3] * SPATIAL_SCALE;
    const float y2 = r[4] * SPATIAL_SCALE;
    const float bin_w = fmaxf(x2 - x1, 1.0f) * (1.0f / POOLED_W);
    const float bin_h = fmaxf(y2 - y1, 1.0f) * (1.0f / POOLED_H);

    const int tid = threadIdx.x;
    if (tid < 14) {
        int p = tid >> 1, i = tid & 1;
        float yy = y1 + (float)p * bin_h + ((float)i + 0.5f) * bin_h * 0.5f;
        bool v = (yy > -1.0f) && (yy < (float)FEAT_H);
        float y = fmaxf(yy, 0.0f);
        int lo = min((int)floorf(y), FEAT_H - 1);
        int hi = min(lo + 1, FEAT_H - 1);
        if (lo >= FEAT_H - 1) y = (float)lo;       // edge snap (reference-exact)
        float l = y - (float)lo;
        s_rowlo[tid] = (unsigned)(lo * (FEAT_W * FEAT_C));
        s_rowhi[tid] = (unsigned)(hi * (FEAT_W * FEAT_C));
        s_ywl[tid] = v ? l : 0.0f;                 // validity folded into weights
        s_ywh[tid] = v ? (1.0f - l) : 0.0f;
    } else if (tid >= 64 && tid < 78) {
        int tt = tid - 64;
        int p = tt >> 1, i = tt & 1;
        float xx = x1 + (float)p * bin_w + ((float)i + 0.5f) * bin_w * 0.5f;
        bool v = (xx > -1.0f) && (xx < (float)FEAT_W);
        float x = fmaxf(xx, 0.0f);
        int lo = min((int)floorf(x), FEAT_W - 1);
        int hi = min(lo + 1, FEAT_W - 1);
        if (lo >= FEAT_W - 1) x = (float)lo;
        float l = x - (float)lo;
        s_collo[tt] = (unsigned)(lo * FEAT_C);
        s_colhi[tt] = (unsigned)(hi * FEAT_C);
        s_xwl[tt] = v ? l : 0.0f;
        s_xwh[tt] = v ? (1.0f - l) : 0.0f;
    }
    __syncthreads();

    const int g = tid & 7;           // channel octet: qc + 8g .. qc + 8g+7
    const int slot = tid >> 3;       // cell slot 0..31
    // 32-bit element offset of this thread's channel octet (fits: 20.5M ushorts)
    const unsigned int cbase = (unsigned)((size_t)b * IMG_USH) + (unsigned)(qc + 8 * g);

#pragma unroll
    for (int k = 0; k < 2; ++k) {
        const int s = slot + 32 * k;
        if (s < 49) {
            const int ph = (s * 37) >> 8;          // s/7 for s<49
            const int pw = s - ph * 7;
            float a0 = 0.f, a1 = 0.f, a2 = 0.f, a3 = 0.f;
            float a4 = 0.f, a5 = 0.f, a6 = 0.f, a7 = 0.f;
#pragma unroll
            for (int iy = 0; iy < 2; ++iy) {
                const int ky = ph * 2 + iy;
                const unsigned int rl = cbase + s_rowlo[ky];
                const unsigned int rh = cbase + s_rowhi[ky];
                const float wyl = s_ywl[ky];
                const float wyh = s_ywh[ky];
#pragma unroll
                for (int ix = 0; ix < 2; ++ix) {
                    const int kx = pw * 2 + ix;
                    const unsigned int cl = s_collo[kx];
                    const unsigned int ch = s_colhi[kx];
                    const float w00 = wyh * s_xwh[kx];
                    const float w01 = wyh * s_xwl[kx];
                    const float w10 = wyl * s_xwh[kx];
                    const float w11 = wyl * s_xwl[kx];
                    uint4 t00 = *(const uint4*)(feat + (size_t)(rl + cl));
                    uint4 t01 = *(const uint4*)(feat + (size_t)(rl + ch));
                    uint4 t10 = *(const uint4*)(feat + (size_t)(rh + cl));
                    uint4 t11 = *(const uint4*)(feat + (size_t)(rh + ch));
                    a0 += w00 * bflo(t00.x) + w01 * bflo(t01.x) + w10 * bflo(t10.x) + w11 * bflo(t11.x);
                    a1 += w00 * bfhi(t00.x) + w01 * bfhi(t01.x) + w10 * bfhi(t10.x) + w11 * bfhi(t11.x);
                    a2 += w00 * bflo(t00.y) + w01 * bflo(t01.y) + w10 * bflo(t10.y) + w11 * bflo(t11.y);
                    a3 += w00 * bfhi(t00.y) + w01 * bfhi(t01.y) + w10 * bfhi(t10.y) + w11 * bfhi(t11.y);
                    a4 += w00 * bflo(t00.z) + w01 * bflo(t01.z) + w10 * bflo(t10.z) + w11 * bflo(t11.z);
                    a5 += w00 * bfhi(t00.z) + w01 * bfhi(t01.z) + w10 * bfhi(t10.z) + w11 * bfhi(t11.z);
                    a6 += w00 * bflo(t00.w) + w01 * bflo(t01.w) + w10 * bflo(t10.w) + w11 * bflo(t11.w);
                    a7 += w00 * bfhi(t00.w) + w01 * bfhi(t01.w) + w10 * bfhi(t10.w) + w11 * bfhi(t11.w);
                }
            }
            const int cb = 8 * g;
            outbuf[(cb + 0) * 49 + s] = a0 * 0.25f;
            outbuf[(cb + 1) * 49 + s] = a1 * 0.25f;
            outbuf[(cb + 2) * 49 + s] = a2 * 0.25f;
            outbuf[(cb + 3) * 49 + s] = a3 * 0.25f;
            outbuf[(cb + 4) * 49 + s] = a4 * 0.25f;
            outbuf[(cb + 5) * 49 + s] = a5 * 0.25f;
            outbuf[(cb + 6) * 49 + s] = a6 * 0.25f;
            outbuf[(cb + 7) * 49 + s] = a7 * 0.25f;
        }
    }
    __syncthreads();

    // flat copy: 3136 floats = 784 float4, fully contiguous per block
    const float4* src = (const float4*)outbuf;
    float4* dst = (float4*)(out + (size_t)(roi * FEAT_C + qc) * 49);
    for (int i = tid; i < 784; i += 256) dst[i] = src[i];
}

// ---------- fallback (direct gather, no workspace) ----------
__device__ __forceinline__ float bilinear_tap(const float* __restrict__ plane,
                                              float y, float x) {
    const int H = FEAT_H, W = FEAT_W;
    if (!(y > -1.0f && y < (float)H && x > -1.0f && x < (float)W)) return 0.0f;
    y = fmaxf(y, 0.0f);
    x = fmaxf(x, 0.0f);
    int y0 = min((int)floorf(y), H - 1);
    int x0 = min((int)floorf(x), W - 1);
    int y1 = min(y0 + 1, H - 1);
    int x1 = min(x0 + 1, W - 1);
    if (y0 >= H - 1) y = (float)y0;
    if (x0 >= W - 1) x = (float)x0;
    float ly = y - (float)y0, lx = x - (float)x0;
    float hy = 1.0f - ly, hx = 1.0f - lx;
    return hy * (hx * plane[y0 * W + x0] + lx * plane[y0 * W + x1]) +
           ly * (hx * plane[y1 * W + x0] + lx * plane[y1 * W + x1]);
}

__global__ __launch_bounds__(256) void roialign_direct(
    const float* __restrict__ features, const float* __restrict__ rois,
    float* __restrict__ out, int num_rois) {
    int i = blockIdx.x * blockDim.x + threadIdx.x;
    int total = num_rois * FEAT_C * 49;
    if (i >= total) return;
    int s = i % 49;
    int t = i / 49;
    int c = t % FEAT_C;
    int roi = t / FEAT_C;
    int ph = s / POOLED_W, pw = s % POOLED_W;
    const float* r = rois + roi * 5;
    int b = (int)r[0];
    float x1 = r[1] * SPATIAL_SCALE, y1 = r[2] * SPATIAL_SCALE;
    float x2 = r[3] * SPATIAL_SCALE, y2 = r[4] * SPATIAL_SCALE;
    float bin_w = fmaxf(x2 - x1, 1.0f) * (1.0f / POOLED_W);
    float bin_h = fmaxf(y2 - y1, 1.0f) * (1.0f / POOLED_H);
    const float* plane = features + ((size_t)(b * FEAT_C + c)) * FEAT_S;
    float acc = 0.0f;
#pragma unroll
    for (int iy = 0; iy < 2; ++iy) {
        float yy = y1 + (float)ph * bin_h + ((float)iy + 0.5f) * bin_h * 0.5f;
#pragma unroll
        for (int ix = 0; ix < 2; ++ix) {
            float xx = x1 + (float)pw * bin_w + ((float)ix + 0.5f) * bin_w * 0.5f;
            acc += bilinear_tap(plane, yy, xx);
        }
    }
    out[i] = acc * 0.25f;
}

extern "C" void kernel_launch(void* const* d_in, const int* in_sizes, int n_in,
                              void* d_out, int out_size, void* d_ws, size_t ws_size,
                              hipStream_t stream) {
    const float* features = (const float*)d_in[0];
    const float* rois = (const float*)d_in[1];
    float* out = (float*)d_out;
    int num_rois = in_sizes[1] / 5;
    size_t nhwc_bytes = (size_t)FEAT_N * IMG_USH * sizeof(unsigned short);  // ~41 MB
    size_t need = nhwc_bytes + (size_t)num_rois * sizeof(int);
    if (ws_size >= need) {
        unsigned short* nhwc = (unsigned short*)d_ws;
        int* perm = (int*)((char*)d_ws + nhwc_bytes);
        nchw_to_nhwc_bf16<<<NTILE, 256, 0, stream>>>(features, nhwc, rois, num_rois,
                                                     perm);
        roialign_main<<<num_rois * 4, 256, 0, stream>>>(nhwc, rois, perm, out, num_rois);
    } else {
        int total = num_rois * FEAT_C * 49;
        roialign_direct<<<(total + 255) / 256, 256, 0, stream>>>(features, rois, out,
                                                                 num_rois);
    }
}